// Round 3
// baseline (120.457 us; speedup 1.0000x reference)
//
#include <hip/hip_runtime.h>
#include <hip/hip_bf16.h>
#include <stdint.h>

// Problem constants: Xp(16384,3) X(8192,3) W(64,8192) eps scalar -> out(16384,64)
#define M_ROWS 16384
#define N_PTS  8192
#define K_OUT  64
#define NSPLIT 8
#define SLICE  (N_PTS / NSPLIT)   // 1024 points per block
#define LSTR   40                 // LDS row stride in shorts (80 B; pad breaks conflicts)

typedef short bf16x8 __attribute__((ext_vector_type(8)));
typedef float f32x4  __attribute__((ext_vector_type(4)));

union ABFrag { bf16x8 v; uint32_t u[4]; uint4 q; };

// pack two f32 -> two bf16 (round-half-up) in one v_perm_b32 (+2 adds)
__device__ __forceinline__ uint32_t pack_bf16_rhu(float a, float b) {
    uint32_t ua = __builtin_bit_cast(uint32_t, a) + 0x8000u;
    uint32_t ub = __builtin_bit_cast(uint32_t, b) + 0x8000u;
    return __builtin_amdgcn_perm(ub, ua, 0x07060302u);
}
// RNE pack (prep / one-time paths)
__device__ __forceinline__ uint32_t pack_bf16_rne(float a, float b) {
    uint32_t ua = __builtin_bit_cast(uint32_t, a);
    ua += 0x7FFFu + ((ua >> 16) & 1u);
    uint32_t ub = __builtin_bit_cast(uint32_t, b);
    ub += 0x7FFFu + ((ub >> 16) & 1u);
    return __builtin_amdgcn_perm(ub, ua, 0x07060302u);
}

// ---------------- prep ----------------
// blocks [0,256):   W -> fragment-linear bf16 Wt (B-frag order for 16x16x32):
//                   Wt uint4 idx (b*4+kt)*64+lane = W[kt*16+(lane&15)][b*32+(lane>>4)*8+j]
// blocks [256,512): zero d_out
// blocks [512,640): point-geometry A-frags Pf: per 16-pt group t, lane (g,i):
//                   g==0: bf16 (x~, y~, z~, b, 1, 0,0,0) for pt=t*16+i (x~=eps*x, b=|x~|^2+1)
//                   g>0 : zeros (unused K lanes of the MFMA)
__global__ __launch_bounds__(256) void rbf_prep(
    const float* __restrict__ Wf, const float* __restrict__ X,
    const float* __restrict__ epsp, float* __restrict__ out,
    uint4* __restrict__ Wt, uint4* __restrict__ Pf)
{
    const int bid = blockIdx.x, tid = threadIdx.x;
    if (bid < 256) {
        const int kt = tid >> 6, lane = tid & 63;
        const int l15 = lane & 15, g = lane >> 4;
        const int row = kt * 16 + l15;
        const int col = bid * 32 + g * 8;
        const float4* src = (const float4*)(Wf + row * N_PTS + col);
        const float4 w0 = src[0], w1 = src[1];
        uint4 p;
        p.x = pack_bf16_rne(w0.x, w0.y);
        p.y = pack_bf16_rne(w0.z, w0.w);
        p.z = pack_bf16_rne(w1.x, w1.y);
        p.w = pack_bf16_rne(w1.z, w1.w);
        Wt[(bid * 4 + kt) * 64 + lane] = p;
    } else if (bid < 512) {
        const int i = ((bid - 256) * 256 + tid) * 4;
        const float4 z = make_float4(0.f, 0.f, 0.f, 0.f);
        float4* o = (float4*)out + i;
        o[0] = z; o[1] = z; o[2] = z; o[3] = z;
    } else {
        const int idx = (bid - 512) * 256 + tid;     // [0, 32768)
        const int lane = idx & 63;
        const int t = idx >> 6;
        const int g = lane >> 4, i = lane & 15;
        uint4 v = make_uint4(0u, 0u, 0u, 0u);
        if (g == 0) {
            const int pt = t * 16 + i;
            const float e = *epsp;
            const float x = X[3 * pt + 0] * e;
            const float y = X[3 * pt + 1] * e;
            const float z = X[3 * pt + 2] * e;
            const float b = fmaf(x, x, fmaf(y, y, fmaf(z, z, 1.0f)));
            v.x = pack_bf16_rne(x, y);
            v.y = pack_bf16_rne(z, b);
            v.z = pack_bf16_rne(1.0f, 0.0f);
        }
        Pf[idx] = v;
    }
}

// ---------------- main ----------------
// 2048 blocks = 256 row-groups x 8 n-slices; 4 waves x 16 rows = 64 rows/block.
// Per 32-pt iter: 2x MFMA1 (geometry -> d^2+1 tiles), sqrt+clamp+pack on VALU,
// LDS round-trip (C/D layout -> A layout), 4x MFMA2 vs fragment-linear W.
__global__ __launch_bounds__(256, 5) void rbf_main(
    const float* __restrict__ Xp, const uint4* __restrict__ Wt,
    const uint4* __restrict__ Pf, const float* __restrict__ epsp,
    float* __restrict__ out)
{
    __shared__ __align__(16) short sPhi[4 * 16 * LSTR];   // 5120 B

    const int tid  = threadIdx.x;
    const int lane = tid & 63;
    const int wv   = tid >> 6;
    const int m    = lane & 15;
    const int g    = lane >> 4;

    const int bid   = blockIdx.x;
    const int ns    = bid & (NSPLIT - 1);
    const int rg    = bid >> 3;
    const int nbase = ns * SLICE;
    const int rowbase = rg * 64 + wv * 16;

    // loop-invariant row-geometry B-frag: k=(-2px,-2py,-2pz,1,a) for column m
    ABFrag b1;
    b1.q = make_uint4(0u, 0u, 0u, 0u);
    if (g == 0) {
        const float e = *epsp;
        const int r = rowbase + m;
        const float px = Xp[3 * r + 0] * e;
        const float py = Xp[3 * r + 1] * e;
        const float pz = Xp[3 * r + 2] * e;
        const float a = fmaf(px, px, fmaf(py, py, pz * pz));
        b1.u[0] = pack_bf16_rne(-2.0f * px, -2.0f * py);
        b1.u[1] = pack_bf16_rne(-2.0f * pz, 1.0f);
        b1.u[2] = pack_bf16_rne(a, 0.0f);
    }

    f32x4 acc0 = {0.f, 0.f, 0.f, 0.f};
    f32x4 acc1 = acc0, acc2 = acc0, acc3 = acc0;

    // point-geometry frags: group stride 64 uint4; slice starts at group nbase/16
    const uint4* pA = Pf + (nbase >> 4) * 64 + lane;
    // fragment-linear W: per-32pt-step stride 256 uint4, kt stride 64
    const uint4* wb = Wt + ns * 32 * 256 + lane;
    short* wrow = sPhi + (wv * 16 + m) * LSTR;

    #pragma unroll 2
    for (int s = 0; s < SLICE / 32; ++s) {
        ABFrag a1a, a1b;
        a1a.q = pA[s * 128];
        a1b.q = pA[s * 128 + 64];

        const uint4* wp = wb + s * 256;
        ABFrag w0, w1, w2, w3;
        w0.q = wp[0];
        w1.q = wp[64];
        w2.q = wp[128];
        w3.q = wp[192];

        const f32x4 zc = {0.f, 0.f, 0.f, 0.f};
        // D1 lane(g,m): d^2+1 for Xp-row (rowbase+m), points 4g+reg (a: 0-15, b: 16-31)
        f32x4 d1a = __builtin_amdgcn_mfma_f32_16x16x32_bf16(a1a.v, b1.v, zc, 0, 0, 0);
        f32x4 d1b = __builtin_amdgcn_mfma_f32_16x16x32_bf16(a1b.v, b1.v, zc, 0, 0, 0);

        float t0 = __builtin_amdgcn_sqrtf(fmaxf(d1a[0], 0.f));
        float t1 = __builtin_amdgcn_sqrtf(fmaxf(d1a[1], 0.f));
        float t2 = __builtin_amdgcn_sqrtf(fmaxf(d1a[2], 0.f));
        float t3 = __builtin_amdgcn_sqrtf(fmaxf(d1a[3], 0.f));
        float t4 = __builtin_amdgcn_sqrtf(fmaxf(d1b[0], 0.f));
        float t5 = __builtin_amdgcn_sqrtf(fmaxf(d1b[1], 0.f));
        float t6 = __builtin_amdgcn_sqrtf(fmaxf(d1b[2], 0.f));
        float t7 = __builtin_amdgcn_sqrtf(fmaxf(d1b[3], 0.f));

        uint2 pa, pb;
        pa.x = pack_bf16_rhu(t0, t1);
        pa.y = pack_bf16_rhu(t2, t3);
        pb.x = pack_bf16_rhu(t4, t5);
        pb.y = pack_bf16_rhu(t6, t7);

        // C/D -> A layout transform through LDS (row = Xp-row m, cols = points 0..31)
        *(uint2*)(wrow + 4 * g)      = pa;   // pts 4g..4g+3
        *(uint2*)(wrow + 16 + 4 * g) = pb;   // pts 16+4g..16+4g+3

        ABFrag a2;
        a2.q = *(const uint4*)(wrow + 8 * g);   // pts 8g..8g+7 for row m

        acc0 = __builtin_amdgcn_mfma_f32_16x16x32_bf16(a2.v, w0.v, acc0, 0, 0, 0);
        acc1 = __builtin_amdgcn_mfma_f32_16x16x32_bf16(a2.v, w1.v, acc1, 0, 0, 0);
        acc2 = __builtin_amdgcn_mfma_f32_16x16x32_bf16(a2.v, w2.v, acc2, 0, 0, 0);
        acc3 = __builtin_amdgcn_mfma_f32_16x16x32_bf16(a2.v, w3.v, acc3, 0, 0, 0);
    }

    // D2: col = kt*16 + m, row = rowbase + g*4 + reg. NSPLIT partials -> atomicAdd.
    float* o = out + (rowbase + g * 4) * K_OUT + m;
    #pragma unroll
    for (int reg = 0; reg < 4; ++reg) {
        atomicAdd(o + reg * K_OUT +  0, acc0[reg]);
        atomicAdd(o + reg * K_OUT + 16, acc1[reg]);
        atomicAdd(o + reg * K_OUT + 32, acc2[reg]);
        atomicAdd(o + reg * K_OUT + 48, acc3[reg]);
    }
}

extern "C" void kernel_launch(void* const* d_in, const int* in_sizes, int n_in,
                              void* d_out, int out_size, void* d_ws, size_t ws_size,
                              hipStream_t stream) {
    (void)in_sizes; (void)n_in; (void)out_size; (void)ws_size;
    const float* Xp  = (const float*)d_in[0];   // (16384,3)
    const float* X   = (const float*)d_in[1];   // (8192,3)
    const float* Wf  = (const float*)d_in[2];   // (64,8192)
    const float* eps = (const float*)d_in[3];   // scalar
    float* out = (float*)d_out;                 // (16384,64)

    // ws: Wt (fragment-linear bf16 W) 1 MiB | Pf (point-geometry A-frags) 512 KiB
    uint4* Wt = (uint4*)d_ws;
    uint4* Pf = (uint4*)((char*)d_ws + (1u << 20));

    rbf_prep<<<dim3(640), dim3(256), 0, stream>>>(Wf, X, eps, out, Wt, Pf);
    rbf_main<<<dim3((M_ROWS / 64) * NSPLIT), dim3(256), 0, stream>>>(Xp, Wt, Pf, eps, out);
}